// Round 1
// baseline (946.908 us; speedup 1.0000x reference)
//
#include <hip/hip_runtime.h>

#define HW 4608
#define CC 128
#define H 48
#define W 96
#define S_WIN 1152
#define SCALE 0.08838834764831845f  // 1/sqrt(128)

// ============ correlation GEMM pass A: row/col exp-sums ============
__global__ __launch_bounds__(256)
void corr_stats(const float* __restrict__ f0, const float* __restrict__ f1,
                float* __restrict__ rowsum, float* __restrict__ colsum)
{
    __shared__ float As[16][64];
    __shared__ float Bs[16][64];
    __shared__ float rp[64], cp[64];
    const int t  = threadIdx.x;
    const int tx = t & 15, ty = t >> 4;
    const int kb = blockIdx.x * 64, qb = blockIdx.y * 64, bb = blockIdx.z;
    const float* A = f0 + (size_t)bb * CC * HW;
    const float* B = f1 + (size_t)bb * CC * HW;

    float acc[4][4] = {};
    const int lr = t >> 4;        // 0..15 (channel row)
    const int lc = (t & 15) * 4;  // 0..60

    for (int k0 = 0; k0 < CC; k0 += 16) {
        __syncthreads();
        *(float4*)&As[lr][lc] = *(const float4*)&A[(size_t)(k0 + lr) * HW + qb + lc];
        *(float4*)&Bs[lr][lc] = *(const float4*)&B[(size_t)(k0 + lr) * HW + kb + lc];
        __syncthreads();
        #pragma unroll
        for (int kk = 0; kk < 16; ++kk) {
            float4 a4 = *(const float4*)&As[kk][ty * 4];
            float4 b4 = *(const float4*)&Bs[kk][tx * 4];
            float av[4] = {a4.x, a4.y, a4.z, a4.w};
            float bv[4] = {b4.x, b4.y, b4.z, b4.w};
            #pragma unroll
            for (int i = 0; i < 4; ++i)
                #pragma unroll
                for (int j = 0; j < 4; ++j) acc[i][j] += av[i] * bv[j];
        }
    }

    if (t < 64) { rp[t] = 0.f; cp[t] = 0.f; }
    __syncthreads();
    float rpart[4] = {}, cpart[4] = {};
    #pragma unroll
    for (int i = 0; i < 4; ++i)
        #pragma unroll
        for (int j = 0; j < 4; ++j) {
            float e = __expf(acc[i][j] * SCALE);
            rpart[i] += e; cpart[j] += e;
        }
    #pragma unroll
    for (int i = 0; i < 4; ++i) atomicAdd(&rp[ty * 4 + i], rpart[i]);
    #pragma unroll
    for (int j = 0; j < 4; ++j) atomicAdd(&cp[tx * 4 + j], cpart[j]);
    __syncthreads();
    if (t < 64)        atomicAdd(&rowsum[(size_t)bb * HW + qb + t], rp[t]);
    else if (t < 128)  atomicAdd(&colsum[(size_t)bb * HW + kb + (t - 64)], cp[t - 64]);
}

// ============ correlation GEMM pass B: dual_prob + flow partials ============
__global__ __launch_bounds__(256)
void corr_final(const float* __restrict__ f0, const float* __restrict__ f1,
                const float* __restrict__ rowsum, const float* __restrict__ colsum,
                float* __restrict__ rowflow, float* __restrict__ colflow,
                float* __restrict__ dual)
{
    __shared__ float As[16][64];
    __shared__ float Bs[16][64];
    __shared__ float lrx[64], lry[64], lcx[64], lcy[64];
    const int t  = threadIdx.x;
    const int tx = t & 15, ty = t >> 4;
    const int kb = blockIdx.x * 64, qb = blockIdx.y * 64, bb = blockIdx.z;
    const float* A = f0 + (size_t)bb * CC * HW;
    const float* B = f1 + (size_t)bb * CC * HW;

    float acc[4][4] = {};
    const int lr = t >> 4;
    const int lc = (t & 15) * 4;

    for (int k0 = 0; k0 < CC; k0 += 16) {
        __syncthreads();
        *(float4*)&As[lr][lc] = *(const float4*)&A[(size_t)(k0 + lr) * HW + qb + lc];
        *(float4*)&Bs[lr][lc] = *(const float4*)&B[(size_t)(k0 + lr) * HW + kb + lc];
        __syncthreads();
        #pragma unroll
        for (int kk = 0; kk < 16; ++kk) {
            float4 a4 = *(const float4*)&As[kk][ty * 4];
            float4 b4 = *(const float4*)&Bs[kk][tx * 4];
            float av[4] = {a4.x, a4.y, a4.z, a4.w};
            float bv[4] = {b4.x, b4.y, b4.z, b4.w};
            #pragma unroll
            for (int i = 0; i < 4; ++i)
                #pragma unroll
                for (int j = 0; j < 4; ++j) acc[i][j] += av[i] * bv[j];
        }
    }

    float rs[4], cs[4];
    #pragma unroll
    for (int i = 0; i < 4; ++i) rs[i] = rowsum[(size_t)bb * HW + qb + ty * 4 + i];
    #pragma unroll
    for (int j = 0; j < 4; ++j) cs[j] = colsum[(size_t)bb * HW + kb + tx * 4 + j];

    float rfx[4] = {}, rfy[4] = {}, cfx[4] = {}, cfy[4] = {};
    #pragma unroll
    for (int i = 0; i < 4; ++i) {
        int q = qb + ty * 4 + i;
        float gqx = (float)(q % W), gqy = (float)(q / W);
        float dv[4];
        #pragma unroll
        for (int j = 0; j < 4; ++j) {
            int k = kb + tx * 4 + j;
            float e  = __expf(acc[i][j] * SCALE);
            float r  = e / rs[i];
            float ce = e / cs[j];
            dv[j] = r * ce;
            float gkx = (float)(k % W), gky = (float)(k / W);
            rfx[i] += r * gkx;  rfy[i] += r * gky;
            cfx[j] += ce * gqx; cfy[j] += ce * gqy;
        }
        *(float4*)&dual[((size_t)bb * HW + q) * HW + kb + tx * 4] =
            make_float4(dv[0], dv[1], dv[2], dv[3]);
    }

    if (t < 64) { lrx[t] = 0.f; lry[t] = 0.f; lcx[t] = 0.f; lcy[t] = 0.f; }
    __syncthreads();
    #pragma unroll
    for (int i = 0; i < 4; ++i) { atomicAdd(&lrx[ty * 4 + i], rfx[i]); atomicAdd(&lry[ty * 4 + i], rfy[i]); }
    #pragma unroll
    for (int j = 0; j < 4; ++j) { atomicAdd(&lcx[tx * 4 + j], cfx[j]); atomicAdd(&lcy[tx * 4 + j], cfy[j]); }
    __syncthreads();
    if (t < 64) {
        atomicAdd(&rowflow[((size_t)bb * HW + qb + t) * 2 + 0], lrx[t]);
        atomicAdd(&rowflow[((size_t)bb * HW + qb + t) * 2 + 1], lry[t]);
    } else if (t < 128) {
        int j = t - 64;
        atomicAdd(&colflow[((size_t)bb * HW + kb + j) * 2 + 0], lcx[j]);
        atomicAdd(&colflow[((size_t)bb * HW + kb + j) * 2 + 1], lcy[j]);
    }
}

// ============ flow finalize: corresp - init_grid, (b,2,h,w) layout ============
__global__ void flow_finalize(const float* __restrict__ rowflow, const float* __restrict__ colflow,
                              float* __restrict__ out /* f01 base; f10 follows */)
{
    int i = blockIdx.x * 256 + threadIdx.x;
    if (i >= 2 * 2 * HW) return;           // b*2*h*w = 18432
    int bb   = i / (2 * HW);
    int rem  = i % (2 * HW);
    int chan = rem / HW;
    int q    = rem % HW;
    float g = (chan == 0) ? (float)(q % W) : (float)(q / W);
    out[i]              = rowflow[((size_t)bb * HW + q) * 2 + chan] - g;
    out[2 * 2 * HW + i] = colflow[((size_t)bb * HW + q) * 2 + chan] - g;
}

// ============ shifted-window attention ============
__global__ __launch_bounds__(256)
void win_attn(const float* __restrict__ Q, const float* __restrict__ K,
              const float* __restrict__ V, const float* __restrict__ mask,
              float* __restrict__ out)
{
    __shared__ float qs[8][128];
    __shared__ float sc[8][S_WIN];
    __shared__ float kv[32][132];   // +4 pad: 4-way instead of 32-way bank conflict

    const int t    = threadIdx.x;
    const int qblk = blockIdx.x;   // 0..143
    const int wb   = blockIdx.y;   // 0..7
    const int bb = wb >> 2, wi = wb & 3, si = wi >> 1, sj = wi & 1;

    const int qi = t >> 5;         // 0..7
    const int kj = t & 31;         // 0..31
    const int qw = qblk * 8 + qi;

    // load Q block (8 x 128)
    {
        int ch = (t & 31) * 4;
        int r = qw / 48, c0 = qw % 48;
        int y = (si * 24 + r + 12) % 48;
        int x = (sj * 48 + c0 + 24) % 96;
        *(float4*)&qs[qi][ch] = *(const float4*)&Q[((size_t)bb * HW + y * 96 + x) * CC + ch];
    }

    // scores: loop K tiles of 32
    for (int kt = 0; kt < 36; ++kt) {
        __syncthreads();
        #pragma unroll
        for (int p = 0; p < 4; ++p) {
            int kr = p * 8 + (t >> 5);
            int ch = (t & 31) * 4;
            int kw = kt * 32 + kr;
            int rk = kw / 48, ck = kw % 48;
            int yk = (si * 24 + rk + 12) % 48;
            int xk = (sj * 48 + ck + 24) % 96;
            *(float4*)&kv[kr][ch] = *(const float4*)&K[((size_t)bb * HW + yk * 96 + xk) * CC + ch];
        }
        __syncthreads();
        float s = 0.f;
        #pragma unroll 8
        for (int ch = 0; ch < 128; ch += 4) {
            float4 a = *(const float4*)&qs[qi][ch];
            float4 b = *(const float4*)&kv[kj][ch];
            s += a.x * b.x + a.y * b.y + a.z * b.z + a.w * b.w;
        }
        int kw = kt * 32 + kj;
        sc[qi][kw] = s * SCALE + mask[((size_t)wi * S_WIN + qw) * S_WIN + kw];
    }
    __syncthreads();

    // softmax per row (32 lanes per row)
    {
        int lane = t & 31;
        float m = -1e30f;
        for (int k = lane; k < S_WIN; k += 32) m = fmaxf(m, sc[qi][k]);
        #pragma unroll
        for (int o = 16; o; o >>= 1) m = fmaxf(m, __shfl_xor(m, o, 32));
        float sum = 0.f;
        for (int k = lane; k < S_WIN; k += 32) {
            float e = __expf(sc[qi][k] - m);
            sc[qi][k] = e; sum += e;
        }
        #pragma unroll
        for (int o = 16; o; o >>= 1) sum += __shfl_xor(sum, o, 32);
        float inv = 1.f / sum;
        for (int k = lane; k < S_WIN; k += 32) sc[qi][k] *= inv;
    }

    // PV: out[8][128], each thread owns (qi, 4 channels)
    float4 acc = make_float4(0.f, 0.f, 0.f, 0.f);
    const int chg = (t & 31) * 4;
    for (int kt = 0; kt < 36; ++kt) {
        __syncthreads();
        #pragma unroll
        for (int p = 0; p < 4; ++p) {
            int kr = p * 8 + (t >> 5);
            int ch = (t & 31) * 4;
            int kw = kt * 32 + kr;
            int rk = kw / 48, ck = kw % 48;
            int yk = (si * 24 + rk + 12) % 48;
            int xk = (sj * 48 + ck + 24) % 96;
            *(float4*)&kv[kr][ch] = *(const float4*)&V[((size_t)bb * HW + yk * 96 + xk) * CC + ch];
        }
        __syncthreads();
        #pragma unroll
        for (int kr = 0; kr < 32; ++kr) {
            float p = sc[qi][kt * 32 + kr];
            float4 v4 = *(const float4*)&kv[kr][chg];
            acc.x += p * v4.x; acc.y += p * v4.y; acc.z += p * v4.z; acc.w += p * v4.w;
        }
    }
    // write out (same roll mapping as input gather)
    {
        int r = qw / 48, c0 = qw % 48;
        int y = (si * 24 + r + 12) % 48;
        int x = (sj * 48 + c0 + 24) % 96;
        *(float4*)&out[((size_t)bb * HW + y * 96 + x) * CC + chg] = acc;
    }
}

extern "C" void kernel_launch(void* const* d_in, const int* in_sizes, int n_in,
                              void* d_out, int out_size, void* d_ws, size_t ws_size,
                              hipStream_t stream)
{
    (void)in_sizes; (void)n_in; (void)out_size; (void)ws_size;
    const float* q    = (const float*)d_in[0];
    const float* k    = (const float*)d_in[1];
    const float* v    = (const float*)d_in[2];
    const float* f0   = (const float*)d_in[3];
    const float* f1   = (const float*)d_in[4];
    const float* mask = (const float*)d_in[5];

    float* out = (float*)d_out;
    const size_t ATTN_SZ = (size_t)2 * HW * CC;   // 1179648
    const size_t FLOW_SZ = (size_t)2 * 2 * HW;    // 18432
    float* f01  = out + ATTN_SZ;
    float* dual = out + ATTN_SZ + 2 * FLOW_SZ;

    float* wsf     = (float*)d_ws;
    float* rowsum  = wsf;                  // 2*4608
    float* colsum  = wsf + 2 * HW;         // 2*4608
    float* rowflow = wsf + 4 * HW;         // 2*4608*2
    float* colflow = wsf + 8 * HW;         // 2*4608*2
    hipMemsetAsync(d_ws, 0, (size_t)12 * HW * sizeof(float), stream);

    win_attn<<<dim3(144, 8), 256, 0, stream>>>(q, k, v, mask, out);
    corr_stats<<<dim3(72, 72, 2), 256, 0, stream>>>(f0, f1, rowsum, colsum);
    corr_final<<<dim3(72, 72, 2), 256, 0, stream>>>(f0, f1, rowsum, colsum,
                                                    rowflow, colflow, dual);
    flow_finalize<<<dim3(72), 256, 0, stream>>>(rowflow, colflow, f01);
}

// Round 2
// 439.212 us; speedup vs baseline: 2.1559x; 2.1559x over previous
//
#include <hip/hip_runtime.h>

#define HW 4608
#define CC 128
#define H 48
#define W 96
#define S_WIN 1152
#define SCALE 0.08838834764831845f  // 1/sqrt(128)

typedef __attribute__((ext_vector_type(8))) short bf16x8;
typedef __attribute__((ext_vector_type(4))) float f32x4;

static __device__ inline short f2bf(float f) {
    unsigned u = __builtin_bit_cast(unsigned, f);
    unsigned r = (u + 0x7fff + ((u >> 16) & 1)) >> 16;   // RNE
    return (short)r;
}

// ============ prep: f0/f1 (b,c,hw) fp32 -> bf16 MFMA A/B-fragment layout ============
// frag element index = b*73728 + (R*4+kc)*64 + lane ; each element = 8 bf16 (16B)
// lane&15 = row/col within 16, lane>>4 = k-group, j = k within group:
//   value = f[b][kc*32 + (lane>>4)*8 + j][R*16 + (lane&15)]
__global__ __launch_bounds__(256)
void prep_frags(const float* __restrict__ f0, const float* __restrict__ f1,
                bf16x8* __restrict__ fragA, bf16x8* __restrict__ fragB)
{
    int gid = blockIdx.x * 256 + threadIdx.x;       // 294912 total
    int tensor = gid / 147456;
    int r2 = gid - tensor * 147456;
    int lane = r2 & 63;
    int kc = (r2 >> 6) & 3;
    int bR = r2 >> 8;                // b*288 + R
    int b = bR / 288;
    int R = bR - b * 288;
    int pos = R * 16 + (lane & 15);
    int c0  = kc * 32 + (lane >> 4) * 8;
    const float* src = (tensor ? f1 : f0) + (size_t)b * CC * HW;
    bf16x8 v;
    #pragma unroll
    for (int j = 0; j < 8; ++j) v[j] = f2bf(src[(size_t)(c0 + j) * HW + pos]);
    (tensor ? fragB : fragA)[r2] = v;
}

// ============ corr pass A: row/col exp-sums via MFMA ============
__global__ __launch_bounds__(256)
void corr_stats(const bf16x8* __restrict__ fragA, const bf16x8* __restrict__ fragB,
                float* __restrict__ rowsum, float* __restrict__ colsum)
{
    __shared__ float rs[128], cs[128];
    const int t = threadIdx.x, lane = t & 63, wave = t >> 6;
    const int wm = wave >> 1, wn = wave & 1;
    const int kt = blockIdx.x, qt = blockIdx.y, b = blockIdx.z;

    const bf16x8* Ab = fragA + (size_t)(b * 288 + qt * 8 + wm * 4) * 256 + lane;
    const bf16x8* Bb = fragB + (size_t)(b * 288 + kt * 8 + wn * 4) * 256 + lane;

    f32x4 acc[4][4] = {};
    #pragma unroll
    for (int kc = 0; kc < 4; ++kc) {
        bf16x8 a[4], bf[4];
        #pragma unroll
        for (int m = 0; m < 4; ++m) a[m]  = Ab[(m * 4 + kc) * 64];
        #pragma unroll
        for (int n = 0; n < 4; ++n) bf[n] = Bb[(n * 4 + kc) * 64];
        #pragma unroll
        for (int m = 0; m < 4; ++m)
            #pragma unroll
            for (int n = 0; n < 4; ++n)
                acc[m][n] = __builtin_amdgcn_mfma_f32_16x16x32_bf16(a[m], bf[n], acc[m][n], 0, 0, 0);
    }

    if (t < 128) { rs[t] = 0.f; cs[t] = 0.f; }
    __syncthreads();

    float cv[4] = {};
    #pragma unroll
    for (int m = 0; m < 4; ++m) {
        float rv[4] = {};
        #pragma unroll
        for (int n = 0; n < 4; ++n)
            #pragma unroll
            for (int r = 0; r < 4; ++r) {
                float ev = __expf(acc[m][n][r] * SCALE);
                rv[r] += ev; cv[n] += ev;
            }
        #pragma unroll
        for (int r = 0; r < 4; ++r) {
            float s = rv[r];
            s += __shfl_xor(s, 1); s += __shfl_xor(s, 2);
            s += __shfl_xor(s, 4); s += __shfl_xor(s, 8);
            if ((lane & 15) == 0)
                atomicAdd(&rs[wm * 64 + m * 16 + (lane >> 4) * 4 + r], s);
        }
    }
    #pragma unroll
    for (int n = 0; n < 4; ++n) {
        float s = cv[n];
        s += __shfl_xor(s, 16); s += __shfl_xor(s, 32);
        if (lane < 16) atomicAdd(&cs[wn * 64 + n * 16 + lane], s);
    }
    __syncthreads();
    if (t < 128)      atomicAdd(&rowsum[(size_t)b * HW + qt * 128 + t], rs[t]);
    else              atomicAdd(&colsum[(size_t)b * HW + kt * 128 + (t - 128)], cs[t - 128]);
}

// ============ corr pass B: dual_prob + flow partials via MFMA ============
__global__ __launch_bounds__(256)
void corr_final(const bf16x8* __restrict__ fragA, const bf16x8* __restrict__ fragB,
                const float* __restrict__ rowsum, const float* __restrict__ colsum,
                float* __restrict__ rowflow, float* __restrict__ colflow,
                float* __restrict__ dual)
{
    __shared__ float sfx[128], sfy[128], scx[128], scy[128];
    const int t = threadIdx.x, lane = t & 63, wave = t >> 6;
    const int wm = wave >> 1, wn = wave & 1;
    const int kt = blockIdx.x, qt = blockIdx.y, b = blockIdx.z;

    const bf16x8* Ab = fragA + (size_t)(b * 288 + qt * 8 + wm * 4) * 256 + lane;
    const bf16x8* Bb = fragB + (size_t)(b * 288 + kt * 8 + wn * 4) * 256 + lane;

    f32x4 acc[4][4] = {};
    #pragma unroll
    for (int kc = 0; kc < 4; ++kc) {
        bf16x8 a[4], bf[4];
        #pragma unroll
        for (int m = 0; m < 4; ++m) a[m]  = Ab[(m * 4 + kc) * 64];
        #pragma unroll
        for (int n = 0; n < 4; ++n) bf[n] = Bb[(n * 4 + kc) * 64];
        #pragma unroll
        for (int m = 0; m < 4; ++m)
            #pragma unroll
            for (int n = 0; n < 4; ++n)
                acc[m][n] = __builtin_amdgcn_mfma_f32_16x16x32_bf16(a[m], bf[n], acc[m][n], 0, 0, 0);
    }

    if (t < 128) { sfx[t] = 0.f; sfy[t] = 0.f; scx[t] = 0.f; scy[t] = 0.f; }
    __syncthreads();

    const int qbase = qt * 128 + wm * 64;
    const int kbase = kt * 128 + wn * 64;

    float cinv[4], gkx[4], gky[4];
    #pragma unroll
    for (int n = 0; n < 4; ++n) {
        int k = kbase + n * 16 + (lane & 15);
        cinv[n] = 1.f / colsum[(size_t)b * HW + k];
        int kyi = k / W;
        gkx[n] = (float)(k - kyi * W); gky[n] = (float)kyi;
    }

    float cfx[4] = {}, cfy[4] = {};
    #pragma unroll
    for (int m = 0; m < 4; ++m) {
        float rinv[4], gqx[4], gqy[4];
        int q0 = qbase + m * 16 + (lane >> 4) * 4;
        #pragma unroll
        for (int r = 0; r < 4; ++r) {
            rinv[r] = 1.f / rowsum[(size_t)b * HW + q0 + r];
            int qyi = (q0 + r) / W;
            gqx[r] = (float)(q0 + r - qyi * W); gqy[r] = (float)qyi;
        }
        float rfx[4] = {}, rfy[4] = {};
        #pragma unroll
        for (int n = 0; n < 4; ++n) {
            #pragma unroll
            for (int r = 0; r < 4; ++r) {
                float ev = __expf(acc[m][n][r] * SCALE);
                float rp = ev * rinv[r];
                float ce = ev * cinv[n];
                dual[((size_t)b * HW + q0 + r) * HW + kbase + n * 16 + (lane & 15)] = rp * ce;
                rfx[r] += rp * gkx[n]; rfy[r] += rp * gky[n];
                cfx[n] += ce * gqx[r]; cfy[n] += ce * gqy[r];
            }
        }
        #pragma unroll
        for (int r = 0; r < 4; ++r) {
            float sx = rfx[r], sy = rfy[r];
            sx += __shfl_xor(sx, 1); sx += __shfl_xor(sx, 2);
            sx += __shfl_xor(sx, 4); sx += __shfl_xor(sx, 8);
            sy += __shfl_xor(sy, 1); sy += __shfl_xor(sy, 2);
            sy += __shfl_xor(sy, 4); sy += __shfl_xor(sy, 8);
            if ((lane & 15) == 0) {
                int row = wm * 64 + m * 16 + (lane >> 4) * 4 + r;
                atomicAdd(&sfx[row], sx); atomicAdd(&sfy[row], sy);
            }
        }
    }
    #pragma unroll
    for (int n = 0; n < 4; ++n) {
        float sx = cfx[n], sy = cfy[n];
        sx += __shfl_xor(sx, 16); sx += __shfl_xor(sx, 32);
        sy += __shfl_xor(sy, 16); sy += __shfl_xor(sy, 32);
        if (lane < 16) {
            int col = wn * 64 + n * 16 + lane;
            atomicAdd(&scx[col], sx); atomicAdd(&scy[col], sy);
        }
    }
    __syncthreads();
    if (t < 128) {
        atomicAdd(&rowflow[((size_t)b * HW + qt * 128 + t) * 2 + 0], sfx[t]);
        atomicAdd(&rowflow[((size_t)b * HW + qt * 128 + t) * 2 + 1], sfy[t]);
    } else {
        int j = t - 128;
        atomicAdd(&colflow[((size_t)b * HW + kt * 128 + j) * 2 + 0], scx[j]);
        atomicAdd(&colflow[((size_t)b * HW + kt * 128 + j) * 2 + 1], scy[j]);
    }
}

// ============ flow finalize: corresp - init_grid, (b,2,h,w) layout ============
__global__ void flow_finalize(const float* __restrict__ rowflow, const float* __restrict__ colflow,
                              float* __restrict__ out /* f01 base; f10 follows */)
{
    int i = blockIdx.x * 256 + threadIdx.x;
    if (i >= 2 * 2 * HW) return;
    int bb   = i / (2 * HW);
    int rem  = i % (2 * HW);
    int chan = rem / HW;
    int q    = rem % HW;
    float g = (chan == 0) ? (float)(q % W) : (float)(q / W);
    out[i]              = rowflow[((size_t)bb * HW + q) * 2 + chan] - g;
    out[2 * 2 * HW + i] = colflow[((size_t)bb * HW + q) * 2 + chan] - g;
}

// ============ shifted-window attention (unchanged) ============
__global__ __launch_bounds__(256)
void win_attn(const float* __restrict__ Q, const float* __restrict__ K,
              const float* __restrict__ V, const float* __restrict__ mask,
              float* __restrict__ out)
{
    __shared__ float qs[8][128];
    __shared__ float sc[8][S_WIN];
    __shared__ float kv[32][132];

    const int t    = threadIdx.x;
    const int qblk = blockIdx.x;
    const int wb   = blockIdx.y;
    const int bb = wb >> 2, wi = wb & 3, si = wi >> 1, sj = wi & 1;

    const int qi = t >> 5;
    const int kj = t & 31;
    const int qw = qblk * 8 + qi;

    {
        int ch = (t & 31) * 4;
        int r = qw / 48, c0 = qw % 48;
        int y = (si * 24 + r + 12) % 48;
        int x = (sj * 48 + c0 + 24) % 96;
        *(float4*)&qs[qi][ch] = *(const float4*)&Q[((size_t)bb * HW + y * 96 + x) * CC + ch];
    }

    for (int kt = 0; kt < 36; ++kt) {
        __syncthreads();
        #pragma unroll
        for (int p = 0; p < 4; ++p) {
            int kr = p * 8 + (t >> 5);
            int ch = (t & 31) * 4;
            int kw = kt * 32 + kr;
            int rk = kw / 48, ck = kw % 48;
            int yk = (si * 24 + rk + 12) % 48;
            int xk = (sj * 48 + ck + 24) % 96;
            *(float4*)&kv[kr][ch] = *(const float4*)&K[((size_t)bb * HW + yk * 96 + xk) * CC + ch];
        }
        __syncthreads();
        float s = 0.f;
        #pragma unroll 8
        for (int ch = 0; ch < 128; ch += 4) {
            float4 a = *(const float4*)&qs[qi][ch];
            float4 b = *(const float4*)&kv[kj][ch];
            s += a.x * b.x + a.y * b.y + a.z * b.z + a.w * b.w;
        }
        int kw = kt * 32 + kj;
        sc[qi][kw] = s * SCALE + mask[((size_t)wi * S_WIN + qw) * S_WIN + kw];
    }
    __syncthreads();

    {
        int lane = t & 31;
        float m = -1e30f;
        for (int k = lane; k < S_WIN; k += 32) m = fmaxf(m, sc[qi][k]);
        #pragma unroll
        for (int o = 16; o; o >>= 1) m = fmaxf(m, __shfl_xor(m, o, 32));
        float sum = 0.f;
        for (int k = lane; k < S_WIN; k += 32) {
            float e = __expf(sc[qi][k] - m);
            sc[qi][k] = e; sum += e;
        }
        #pragma unroll
        for (int o = 16; o; o >>= 1) sum += __shfl_xor(sum, o, 32);
        float inv = 1.f / sum;
        for (int k = lane; k < S_WIN; k += 32) sc[qi][k] *= inv;
    }

    float4 acc = make_float4(0.f, 0.f, 0.f, 0.f);
    const int chg = (t & 31) * 4;
    for (int kt = 0; kt < 36; ++kt) {
        __syncthreads();
        #pragma unroll
        for (int p = 0; p < 4; ++p) {
            int kr = p * 8 + (t >> 5);
            int ch = (t & 31) * 4;
            int kw = kt * 32 + kr;
            int rk = kw / 48, ck = kw % 48;
            int yk = (si * 24 + rk + 12) % 48;
            int xk = (sj * 48 + ck + 24) % 96;
            *(float4*)&kv[kr][ch] = *(const float4*)&V[((size_t)bb * HW + yk * 96 + xk) * CC + ch];
        }
        __syncthreads();
        #pragma unroll
        for (int kr = 0; kr < 32; ++kr) {
            float p = sc[qi][kt * 32 + kr];
            float4 v4 = *(const float4*)&kv[kr][chg];
            acc.x += p * v4.x; acc.y += p * v4.y; acc.z += p * v4.z; acc.w += p * v4.w;
        }
    }
    {
        int r = qw / 48, c0 = qw % 48;
        int y = (si * 24 + r + 12) % 48;
        int x = (sj * 48 + c0 + 24) % 96;
        *(float4*)&out[((size_t)bb * HW + y * 96 + x) * CC + chg] = acc;
    }
}

extern "C" void kernel_launch(void* const* d_in, const int* in_sizes, int n_in,
                              void* d_out, int out_size, void* d_ws, size_t ws_size,
                              hipStream_t stream)
{
    (void)in_sizes; (void)n_in; (void)out_size; (void)ws_size;
    const float* q    = (const float*)d_in[0];
    const float* k    = (const float*)d_in[1];
    const float* v    = (const float*)d_in[2];
    const float* f0   = (const float*)d_in[3];
    const float* f1   = (const float*)d_in[4];
    const float* mask = (const float*)d_in[5];

    float* out = (float*)d_out;
    const size_t ATTN_SZ = (size_t)2 * HW * CC;
    const size_t FLOW_SZ = (size_t)2 * 2 * HW;
    float* f01  = out + ATTN_SZ;
    float* dual = out + ATTN_SZ + 2 * FLOW_SZ;

    // ws layout: fragA (2359296 B) | fragB (2359296 B) | sums/flows (12*HW floats)
    char* wsb = (char*)d_ws;
    bf16x8* fragA = (bf16x8*)wsb;
    bf16x8* fragB = (bf16x8*)(wsb + 2359296);
    float* wsf     = (float*)(wsb + 2 * 2359296);
    float* rowsum  = wsf;
    float* colsum  = wsf + 2 * HW;
    float* rowflow = wsf + 4 * HW;
    float* colflow = wsf + 8 * HW;
    hipMemsetAsync(wsf, 0, (size_t)12 * HW * sizeof(float), stream);

    prep_frags<<<dim3(1152), 256, 0, stream>>>(f0, f1, fragA, fragB);
    win_attn<<<dim3(144, 8), 256, 0, stream>>>(q, k, v, mask, out);
    corr_stats<<<dim3(36, 36, 2), 256, 0, stream>>>(fragA, fragB, rowsum, colsum);
    corr_final<<<dim3(36, 36, 2), 256, 0, stream>>>(fragA, fragB, rowsum, colsum,
                                                    rowflow, colflow, dual);
    flow_finalize<<<dim3(72), 256, 0, stream>>>(rowflow, colflow, f01);
}

// Round 3
// 140.979 us; speedup vs baseline: 6.7167x; 3.1154x over previous
//
#include <hip/hip_runtime.h>

#define HW 4608
#define CC 128
#define H 48
#define W 96
#define S_WIN 1152
#define SCALE 0.08838834764831845f  // 1/sqrt(128)

typedef __attribute__((ext_vector_type(8))) short bf16x8;
typedef __attribute__((ext_vector_type(4))) float f32x4;

static __device__ inline short f2bf(float f) {
    unsigned u = __builtin_bit_cast(unsigned, f);
    unsigned r = (u + 0x7fff + ((u >> 16) & 1)) >> 16;   // RNE
    return (short)r;
}

// ============ corr prep: f0/f1 (b,c,hw) fp32 -> bf16 MFMA frag layout (LDS-staged) ============
// frag idx = ((b*288 + R)*4 + kc)*64 + lane ; elem j: src[(kc*32+(lane>>4)*8+j)*HW + R*16+(lane&15)]
__global__ __launch_bounds__(256)
void prep_corr(const float* __restrict__ f0, const float* __restrict__ f1,
               bf16x8* __restrict__ fragA, bf16x8* __restrict__ fragB)
{
    __shared__ float vt[32][68];
    const int t = threadIdx.x;
    const int pt = blockIdx.x;           // 0..71 : positions pt*64..+64
    const int z  = blockIdx.y;           // 0..15
    const int tensor = z >> 3, b = (z >> 2) & 1, kc = z & 3;
    const float* src = (tensor ? f1 : f0) + (size_t)b * CC * HW + (size_t)kc * 32 * HW + pt * 64;
    {
        int ch = t >> 4;          // 0..15
        int c4 = (t & 15) * 4;
        *(float4*)&vt[ch][c4]      = *(const float4*)&src[(size_t)ch * HW + c4];
        *(float4*)&vt[ch + 16][c4] = *(const float4*)&src[(size_t)(ch + 16) * HW + c4];
    }
    __syncthreads();
    int Rloc = t >> 6, lane = t & 63;
    int R = pt * 4 + Rloc;
    bf16x8 v;
    #pragma unroll
    for (int j = 0; j < 8; ++j) v[j] = f2bf(vt[(lane >> 4) * 8 + j][Rloc * 16 + (lane & 15)]);
    (tensor ? fragB : fragA)[((size_t)(b * 288 + R) * 4 + kc) * 64 + lane] = v;
}

// ============ attn prep: Q/K/V rolled+windowed -> bf16 frags ============
// q/k frag idx = ((wb*72 + R)*4 + kc)*64 + lane : row=R*16+(lane&15) [win pos], ch=kc*32+(lane>>4)*8+j
// v   frag idx = ((wb*8 + dB)*36 + kc)*64 + lane : d=dB*16+(lane&15), k=kc*32+(lane>>4)*8+j [win pos]
__global__ __launch_bounds__(256)
void prep_qkv(const float* __restrict__ Q, const float* __restrict__ K, const float* __restrict__ V,
              bf16x8* __restrict__ qfrag, bf16x8* __restrict__ kfrag, bf16x8* __restrict__ vfrag)
{
    __shared__ float vt[32][132];
    const int t  = threadIdx.x;
    const int R2 = blockIdx.x;   // 0..35 : window positions R2*32..+32
    const int z  = blockIdx.y;   // 0..23 : tensor*8 + wb
    const int tensor = z >> 3, wb = z & 7;
    const int bb = wb >> 2, wi = wb & 3, si = wi >> 1, sj = wi & 1;
    const float* src = (tensor == 0 ? Q : (tensor == 1 ? K : V)) + (size_t)bb * HW * CC;
    {
        int row = t >> 3;             // 0..31
        int c16 = (t & 7) * 16;       // 0..112
        int qw = R2 * 32 + row;
        int rr = qw / 48, cc = qw - rr * 48;
        int y = (si * 24 + rr + 12) % 48;
        int x = (sj * 48 + cc + 24) % 96;
        const float* rp = src + ((size_t)y * 96 + x) * CC + c16;
        #pragma unroll
        for (int u = 0; u < 4; ++u)
            *(float4*)&vt[row][c16 + u * 4] = *(const float4*)&rp[u * 4];
    }
    __syncthreads();
    if (tensor < 2) {
        bf16x8* frag = tensor == 0 ? qfrag : kfrag;
        #pragma unroll
        for (int e2 = 0; e2 < 2; ++e2) {
            int e = t + e2 * 256;
            int Rloc = e >> 8, kc = (e >> 6) & 3, lane = e & 63;
            int R = R2 * 2 + Rloc;
            bf16x8 v;
            #pragma unroll
            for (int j = 0; j < 8; ++j)
                v[j] = f2bf(vt[Rloc * 16 + (lane & 15)][kc * 32 + (lane >> 4) * 8 + j]);
            frag[((size_t)(wb * 72 + R) * 4 + kc) * 64 + lane] = v;
        }
    } else {
        #pragma unroll
        for (int e2 = 0; e2 < 2; ++e2) {
            int e = t + e2 * 256;
            int dB = e >> 6, lane = e & 63;
            bf16x8 v;
            #pragma unroll
            for (int j = 0; j < 8; ++j)
                v[j] = f2bf(vt[(lane >> 4) * 8 + j][dB * 16 + (lane & 15)]);
            vfrag[((size_t)(wb * 8 + dB) * 36 + R2) * 64 + lane] = v;
        }
    }
}

// ============ window attention via MFMA ============
__global__ __launch_bounds__(512)
void win_attn(const bf16x8* __restrict__ qfrag, const bf16x8* __restrict__ kfrag,
              const bf16x8* __restrict__ vfrag, float* __restrict__ out)
{
    __shared__ __align__(16) short Psh[32 * 1152];   // P[q][k] bf16, XOR-swizzled
    __shared__ unsigned char codes[S_WIN];
    __shared__ float rsum_sh[32];

    const int t = threadIdx.x, lane = t & 63, w = t >> 6;
    const int qt = blockIdx.x, wb = blockIdx.y;
    const int bb = wb >> 2, wi = wb & 3, si = wi >> 1, sj = wi & 1;

    if (t < 32) rsum_sh[t] = 0.f;
    for (int i = t; i < S_WIN; i += 512) {
        int r = i / 48, c = i - r * 48;
        int rb = si ? (r >= 12) : 0;
        int cb = sj ? (c >= 24) : 0;
        codes[i] = (unsigned char)(rb | (cb << 1));
    }
    __syncthreads();

    // Q fragments for this 32-q tile
    bf16x8 qf[2][4];
    {
        const bf16x8* qb = qfrag + ((size_t)(wb * 72 + qt * 2) * 4) * 64 + lane;
        #pragma unroll
        for (int qh = 0; qh < 2; ++qh)
            #pragma unroll
            for (int kc = 0; kc < 4; ++kc) qf[qh][kc] = qb[(qh * 4 + kc) * 64];
    }
    int qcode[2];
    qcode[0] = codes[qt * 32 + (lane & 15)];
    qcode[1] = codes[qt * 32 + 16 + (lane & 15)];

    char* Pb = (char*)Psh;
    float rsum[2] = {0.f, 0.f};

    // Phase 1: S^T = mfma(K, Q) -> col=q (lane&15), row=k; exp; store P to LDS
    for (int kt = 0; kt < 9; ++kt) {
        int Rk = w * 9 + kt;
        bf16x8 kf[4];
        const bf16x8* kb = kfrag + ((size_t)(wb * 72 + Rk) * 4) * 64 + lane;
        #pragma unroll
        for (int kc = 0; kc < 4; ++kc) kf[kc] = kb[kc * 64];
        int k0 = Rk * 16 + (lane >> 4) * 4;
        int kcd[4];
        #pragma unroll
        for (int r = 0; r < 4; ++r) kcd[r] = codes[k0 + r];
        #pragma unroll
        for (int qh = 0; qh < 2; ++qh) {
            f32x4 acc = {0.f, 0.f, 0.f, 0.f};
            #pragma unroll
            for (int kc = 0; kc < 4; ++kc)
                acc = __builtin_amdgcn_mfma_f32_16x16x32_bf16(kf[kc], qf[qh][kc], acc, 0, 0, 0);
            float ev[4];
            #pragma unroll
            for (int r = 0; r < 4; ++r) {
                ev[r] = (kcd[r] == qcode[qh]) ? __expf(acc[r] * SCALE) : 0.f;
                rsum[qh] += ev[r];
            }
            unsigned lo = (unsigned)(unsigned short)f2bf(ev[0]) | ((unsigned)(unsigned short)f2bf(ev[1]) << 16);
            unsigned hi = (unsigned)(unsigned short)f2bf(ev[2]) | ((unsigned)(unsigned short)f2bf(ev[3]) << 16);
            int qloc = qh * 16 + (lane & 15);
            int off = (qloc * 2304 + k0 * 2) ^ ((qloc & 7) << 4);
            *(uint2*)(Pb + off) = make_uint2(lo, hi);
        }
    }
    #pragma unroll
    for (int qh = 0; qh < 2; ++qh) {
        float s = rsum[qh];
        s += __shfl_xor(s, 16); s += __shfl_xor(s, 32);
        if (lane < 16) atomicAdd(&rsum_sh[qh * 16 + lane], s);
    }
    __syncthreads();

    // Phase 2: PV. wave w owns d-slice [w*16, w*16+16)
    f32x4 pv[2] = {};
    const bf16x8* vb = vfrag + ((size_t)(wb * 8 + w) * 36) * 64 + lane;
    for (int kc = 0; kc < 36; ++kc) {
        bf16x8 vf = vb[kc * 64];
        #pragma unroll
        for (int qh = 0; qh < 2; ++qh) {
            int qloc = qh * 16 + (lane & 15);
            int off = (qloc * 2304 + kc * 64 + (lane >> 4) * 16) ^ ((qloc & 7) << 4);
            bf16x8 pf = *(const bf16x8*)(Pb + off);
            pv[qh] = __builtin_amdgcn_mfma_f32_16x16x32_bf16(pf, vf, pv[qh], 0, 0, 0);
        }
    }
    // epilogue: normalize + scatter to rolled positions
    #pragma unroll
    for (int qh = 0; qh < 2; ++qh) {
        #pragma unroll
        for (int r = 0; r < 4; ++r) {
            int qloc = qh * 16 + (lane >> 4) * 4 + r;
            float val = pv[qh][r] / rsum_sh[qloc];
            int qw = qt * 32 + qloc;
            int rr = qw / 48, cc2 = qw - rr * 48;
            int y = (si * 24 + rr + 12) % 48;
            int x = (sj * 48 + cc2 + 24) % 96;
            out[((size_t)bb * HW + y * 96 + x) * CC + w * 16 + (lane & 15)] = val;
        }
    }
}

// ============ corr pass A: row/col exp-sums via MFMA ============
__global__ __launch_bounds__(256)
void corr_stats(const bf16x8* __restrict__ fragA, const bf16x8* __restrict__ fragB,
                float* __restrict__ rowsum, float* __restrict__ colsum)
{
    __shared__ float rs[128], cs[128];
    const int t = threadIdx.x, lane = t & 63, wave = t >> 6;
    const int wm = wave >> 1, wn = wave & 1;
    const int kt = blockIdx.x, qt = blockIdx.y, b = blockIdx.z;

    const bf16x8* Ab = fragA + (size_t)(b * 288 + qt * 8 + wm * 4) * 256 + lane;
    const bf16x8* Bb = fragB + (size_t)(b * 288 + kt * 8 + wn * 4) * 256 + lane;

    f32x4 acc[4][4] = {};
    #pragma unroll
    for (int kc = 0; kc < 4; ++kc) {
        bf16x8 a[4], bf[4];
        #pragma unroll
        for (int m = 0; m < 4; ++m) a[m]  = Ab[(m * 4 + kc) * 64];
        #pragma unroll
        for (int n = 0; n < 4; ++n) bf[n] = Bb[(n * 4 + kc) * 64];
        #pragma unroll
        for (int m = 0; m < 4; ++m)
            #pragma unroll
            for (int n = 0; n < 4; ++n)
                acc[m][n] = __builtin_amdgcn_mfma_f32_16x16x32_bf16(a[m], bf[n], acc[m][n], 0, 0, 0);
    }

    if (t < 128) { rs[t] = 0.f; cs[t] = 0.f; }
    __syncthreads();

    float cv[4] = {};
    #pragma unroll
    for (int m = 0; m < 4; ++m) {
        float rv[4] = {};
        #pragma unroll
        for (int n = 0; n < 4; ++n)
            #pragma unroll
            for (int r = 0; r < 4; ++r) {
                float ev = __expf(acc[m][n][r] * SCALE);
                rv[r] += ev; cv[n] += ev;
            }
        #pragma unroll
        for (int r = 0; r < 4; ++r) {
            float s = rv[r];
            s += __shfl_xor(s, 1); s += __shfl_xor(s, 2);
            s += __shfl_xor(s, 4); s += __shfl_xor(s, 8);
            if ((lane & 15) == 0)
                atomicAdd(&rs[wm * 64 + m * 16 + (lane >> 4) * 4 + r], s);
        }
    }
    #pragma unroll
    for (int n = 0; n < 4; ++n) {
        float s = cv[n];
        s += __shfl_xor(s, 16); s += __shfl_xor(s, 32);
        if (lane < 16) atomicAdd(&cs[wn * 64 + n * 16 + lane], s);
    }
    __syncthreads();
    if (t < 128)      atomicAdd(&rowsum[(size_t)b * HW + qt * 128 + t], rs[t]);
    else              atomicAdd(&colsum[(size_t)b * HW + kt * 128 + (t - 128)], cs[t - 128]);
}

// ============ corr pass B: dual_prob + flow partials via MFMA ============
__global__ __launch_bounds__(256)
void corr_final(const bf16x8* __restrict__ fragA, const bf16x8* __restrict__ fragB,
                const float* __restrict__ rowsum, const float* __restrict__ colsum,
                float* __restrict__ rowflow, float* __restrict__ colflow,
                float* __restrict__ dual)
{
    __shared__ float sfx[128], sfy[128], scx[128], scy[128];
    const int t = threadIdx.x, lane = t & 63, wave = t >> 6;
    const int wm = wave >> 1, wn = wave & 1;
    const int kt = blockIdx.x, qt = blockIdx.y, b = blockIdx.z;

    const bf16x8* Ab = fragA + (size_t)(b * 288 + qt * 8 + wm * 4) * 256 + lane;
    const bf16x8* Bb = fragB + (size_t)(b * 288 + kt * 8 + wn * 4) * 256 + lane;

    f32x4 acc[4][4] = {};
    #pragma unroll
    for (int kc = 0; kc < 4; ++kc) {
        bf16x8 a[4], bf[4];
        #pragma unroll
        for (int m = 0; m < 4; ++m) a[m]  = Ab[(m * 4 + kc) * 64];
        #pragma unroll
        for (int n = 0; n < 4; ++n) bf[n] = Bb[(n * 4 + kc) * 64];
        #pragma unroll
        for (int m = 0; m < 4; ++m)
            #pragma unroll
            for (int n = 0; n < 4; ++n)
                acc[m][n] = __builtin_amdgcn_mfma_f32_16x16x32_bf16(a[m], bf[n], acc[m][n], 0, 0, 0);
    }

    if (t < 128) { sfx[t] = 0.f; sfy[t] = 0.f; scx[t] = 0.f; scy[t] = 0.f; }
    __syncthreads();

    const int qbase = qt * 128 + wm * 64;
    const int kbase = kt * 128 + wn * 64;

    float cinv[4], gkx[4], gky[4];
    #pragma unroll
    for (int n = 0; n < 4; ++n) {
        int k = kbase + n * 16 + (lane & 15);
        cinv[n] = 1.f / colsum[(size_t)b * HW + k];
        int kyi = k / W;
        gkx[n] = (float)(k - kyi * W); gky[n] = (float)kyi;
    }

    float cfx[4] = {}, cfy[4] = {};
    #pragma unroll
    for (int m = 0; m < 4; ++m) {
        float rinv[4], gqx[4], gqy[4];
        int q0 = qbase + m * 16 + (lane >> 4) * 4;
        #pragma unroll
        for (int r = 0; r < 4; ++r) {
            rinv[r] = 1.f / rowsum[(size_t)b * HW + q0 + r];
            int qyi = (q0 + r) / W;
            gqx[r] = (float)(q0 + r - qyi * W); gqy[r] = (float)qyi;
        }
        float rfx[4] = {}, rfy[4] = {};
        #pragma unroll
        for (int n = 0; n < 4; ++n) {
            #pragma unroll
            for (int r = 0; r < 4; ++r) {
                float ev = __expf(acc[m][n][r] * SCALE);
                float rp = ev * rinv[r];
                float ce = ev * cinv[n];
                dual[((size_t)b * HW + q0 + r) * HW + kbase + n * 16 + (lane & 15)] = rp * ce;
                rfx[r] += rp * gkx[n]; rfy[r] += rp * gky[n];
                cfx[n] += ce * gqx[r]; cfy[n] += ce * gqy[r];
            }
        }
        #pragma unroll
        for (int r = 0; r < 4; ++r) {
            float sx = rfx[r], sy = rfy[r];
            sx += __shfl_xor(sx, 1); sx += __shfl_xor(sx, 2);
            sx += __shfl_xor(sx, 4); sx += __shfl_xor(sx, 8);
            sy += __shfl_xor(sy, 1); sy += __shfl_xor(sy, 2);
            sy += __shfl_xor(sy, 4); sy += __shfl_xor(sy, 8);
            if ((lane & 15) == 0) {
                int row = wm * 64 + m * 16 + (lane >> 4) * 4 + r;
                atomicAdd(&sfx[row], sx); atomicAdd(&sfy[row], sy);
            }
        }
    }
    #pragma unroll
    for (int n = 0; n < 4; ++n) {
        float sx = cfx[n], sy = cfy[n];
        sx += __shfl_xor(sx, 16); sx += __shfl_xor(sx, 32);
        sy += __shfl_xor(sy, 16); sy += __shfl_xor(sy, 32);
        if (lane < 16) {
            int col = wn * 64 + n * 16 + lane;
            atomicAdd(&scx[col], sx); atomicAdd(&scy[col], sy);
        }
    }
    __syncthreads();
    if (t < 128) {
        atomicAdd(&rowflow[((size_t)b * HW + qt * 128 + t) * 2 + 0], sfx[t]);
        atomicAdd(&rowflow[((size_t)b * HW + qt * 128 + t) * 2 + 1], sfy[t]);
    } else {
        int j = t - 128;
        atomicAdd(&colflow[((size_t)b * HW + kt * 128 + j) * 2 + 0], scx[j]);
        atomicAdd(&colflow[((size_t)b * HW + kt * 128 + j) * 2 + 1], scy[j]);
    }
}

// ============ flow finalize ============
__global__ void flow_finalize(const float* __restrict__ rowflow, const float* __restrict__ colflow,
                              float* __restrict__ out)
{
    int i = blockIdx.x * 256 + threadIdx.x;
    if (i >= 2 * 2 * HW) return;
    int bb   = i / (2 * HW);
    int rem  = i % (2 * HW);
    int chan = rem / HW;
    int q    = rem % HW;
    float g = (chan == 0) ? (float)(q % W) : (float)(q / W);
    out[i]              = rowflow[((size_t)bb * HW + q) * 2 + chan] - g;
    out[2 * 2 * HW + i] = colflow[((size_t)bb * HW + q) * 2 + chan] - g;
}

extern "C" void kernel_launch(void* const* d_in, const int* in_sizes, int n_in,
                              void* d_out, int out_size, void* d_ws, size_t ws_size,
                              hipStream_t stream)
{
    (void)in_sizes; (void)n_in; (void)out_size; (void)ws_size;
    const float* q    = (const float*)d_in[0];
    const float* k    = (const float*)d_in[1];
    const float* v    = (const float*)d_in[2];
    const float* f0   = (const float*)d_in[3];
    const float* f1   = (const float*)d_in[4];

    float* out = (float*)d_out;
    const size_t ATTN_SZ = (size_t)2 * HW * CC;
    const size_t FLOW_SZ = (size_t)2 * 2 * HW;
    float* f01  = out + ATTN_SZ;
    float* dual = out + ATTN_SZ + 2 * FLOW_SZ;

    // ws: cfragA | cfragB | qfrag | kfrag | vfrag (each 2359296 B) | float accumulators
    const size_t FR = 2359296;
    char* wsb = (char*)d_ws;
    bf16x8* cfragA = (bf16x8*)(wsb);
    bf16x8* cfragB = (bf16x8*)(wsb + FR);
    bf16x8* qfrag  = (bf16x8*)(wsb + 2 * FR);
    bf16x8* kfrag  = (bf16x8*)(wsb + 3 * FR);
    bf16x8* vfrag  = (bf16x8*)(wsb + 4 * FR);
    float* wsf     = (float*)(wsb + 5 * FR);
    float* rowsum  = wsf;
    float* colsum  = wsf + 2 * HW;
    float* rowflow = wsf + 4 * HW;
    float* colflow = wsf + 8 * HW;
    hipMemsetAsync(wsf, 0, (size_t)12 * HW * sizeof(float), stream);

    prep_corr<<<dim3(72, 16), 256, 0, stream>>>(f0, f1, cfragA, cfragB);
    prep_qkv<<<dim3(36, 24), 256, 0, stream>>>(q, k, v, qfrag, kfrag, vfrag);
    win_attn<<<dim3(36, 8), 512, 0, stream>>>(qfrag, kfrag, vfrag, out);
    corr_stats<<<dim3(36, 36, 2), 256, 0, stream>>>(cfragA, cfragB, rowsum, colsum);
    corr_final<<<dim3(36, 36, 2), 256, 0, stream>>>(cfragA, cfragB, rowsum, colsum,
                                                    rowflow, colflow, dual);
    flow_finalize<<<dim3(72), 256, 0, stream>>>(rowflow, colflow, f01);
}

// Round 4
// 133.813 us; speedup vs baseline: 7.0764x; 1.0536x over previous
//
#include <hip/hip_runtime.h>

#define HW 4608
#define CC 128
#define H 48
#define W 96
#define S_WIN 1152
#define SCALE 0.08838834764831845f  // 1/sqrt(128)

typedef __attribute__((ext_vector_type(8))) short bf16x8;
typedef __attribute__((ext_vector_type(4))) float f32x4;

static __device__ inline short f2bf(float f) {
    unsigned u = __builtin_bit_cast(unsigned, f);
    unsigned r = (u + 0x7fff + ((u >> 16) & 1)) >> 16;   // RNE
    return (short)r;
}

// ============ merged prep: corr frags + qkv frags + ws zeroing ============
// corr frag idx = ((b*288+R)*4+kc)*64+lane ; elem j: f[(kc*32+(lane>>4)*8+j)*HW + R*16+(lane&15)]
// q/k frag idx = ((wb*72+R)*4+kc)*64+lane : row=R*16+(lane&15) [win pos], ch=kc*32+(lane>>4)*8+j
// v   frag idx = ((wb*8+dB)*36+kc)*64+lane : d=dB*16+(lane&15), k=kc*32+(lane>>4)*8+j [win pos]
__global__ __launch_bounds__(256)
void prep_all(const float* __restrict__ Q, const float* __restrict__ K, const float* __restrict__ V,
              const float* __restrict__ f0, const float* __restrict__ f1,
              bf16x8* __restrict__ cfragA, bf16x8* __restrict__ cfragB,
              bf16x8* __restrict__ qfrag, bf16x8* __restrict__ kfrag, bf16x8* __restrict__ vfrag,
              float* __restrict__ wsf)
{
    __shared__ float vt[32][132];
    const int bx = blockIdx.x;
    const int t = threadIdx.x;

    if (bx < 1152) {
        // zero accumulators (12*HW = 55296 floats over first 216 blocks)
        int zi = bx * 256 + t;
        if (zi < 12 * HW) wsf[zi] = 0.f;
        // ---- corr prep ----
        const int pt = bx % 72;              // positions pt*64..+64
        const int z  = bx / 72;              // 0..15
        const int tensor = z >> 3, b = (z >> 2) & 1, kc = z & 3;
        const float* src = (tensor ? f1 : f0) + (size_t)b * CC * HW + (size_t)kc * 32 * HW + pt * 64;
        {
            int ch = t >> 4;          // 0..15
            int c4 = (t & 15) * 4;
            *(float4*)&vt[ch][c4]      = *(const float4*)&src[(size_t)ch * HW + c4];
            *(float4*)&vt[ch + 16][c4] = *(const float4*)&src[(size_t)(ch + 16) * HW + c4];
        }
        __syncthreads();
        int Rloc = t >> 6, lane = t & 63;
        int R = pt * 4 + Rloc;
        bf16x8 v;
        #pragma unroll
        for (int j = 0; j < 8; ++j) v[j] = f2bf(vt[(lane >> 4) * 8 + j][Rloc * 16 + (lane & 15)]);
        (tensor ? cfragB : cfragA)[((size_t)(b * 288 + R) * 4 + kc) * 64 + lane] = v;
    } else {
        // ---- qkv prep ----
        const int bx2 = bx - 1152;
        const int R2 = bx2 % 36;     // window positions R2*32..+32
        const int z  = bx2 / 36;     // 0..23 : tensor*8 + wb
        const int tensor = z >> 3, wb = z & 7;
        const int bb = wb >> 2, wi = wb & 3, si = wi >> 1, sj = wi & 1;
        const float* src = (tensor == 0 ? Q : (tensor == 1 ? K : V)) + (size_t)bb * HW * CC;
        {
            int row = t >> 3;             // 0..31
            int c16 = (t & 7) * 16;       // 0..112
            int qw = R2 * 32 + row;
            int rr = qw / 48, cc = qw - rr * 48;
            int y = (si * 24 + rr + 12) % 48;
            int x = (sj * 48 + cc + 24) % 96;
            const float* rp = src + ((size_t)y * 96 + x) * CC + c16;
            #pragma unroll
            for (int u = 0; u < 4; ++u)
                *(float4*)&vt[row][c16 + u * 4] = *(const float4*)&rp[u * 4];
        }
        __syncthreads();
        if (tensor < 2) {
            bf16x8* frag = tensor == 0 ? qfrag : kfrag;
            #pragma unroll
            for (int e2 = 0; e2 < 2; ++e2) {
                int e = t + e2 * 256;
                int Rloc = e >> 8, kc = (e >> 6) & 3, lane = e & 63;
                int R = R2 * 2 + Rloc;
                bf16x8 v;
                #pragma unroll
                for (int j = 0; j < 8; ++j)
                    v[j] = f2bf(vt[Rloc * 16 + (lane & 15)][kc * 32 + (lane >> 4) * 8 + j]);
                frag[((size_t)(wb * 72 + R) * 4 + kc) * 64 + lane] = v;
            }
        } else {
            #pragma unroll
            for (int e2 = 0; e2 < 2; ++e2) {
                int e = t + e2 * 256;
                int dB = e >> 6, lane = e & 63;
                bf16x8 v;
                #pragma unroll
                for (int j = 0; j < 8; ++j)
                    v[j] = f2bf(vt[(lane >> 4) * 8 + j][dB * 16 + (lane & 15)]);
                vfrag[((size_t)(wb * 8 + dB) * 36 + R2) * 64 + lane] = v;
            }
        }
    }
}

// ============ window attention via MFMA: 16-q-row tiles ============
__global__ __launch_bounds__(512)
void win_attn(const bf16x8* __restrict__ qfrag, const bf16x8* __restrict__ kfrag,
              const bf16x8* __restrict__ vfrag, float* __restrict__ out)
{
    __shared__ __align__(16) short Psh[16 * 1152];   // 36 KB, XOR-swizzled
    __shared__ unsigned char codes[S_WIN];
    __shared__ float rsum_sh[16];

    const int t = threadIdx.x, lane = t & 63, w = t >> 6;
    const int qt = blockIdx.x;     // 0..71
    const int wb = blockIdx.y;     // 0..7
    const int bb = wb >> 2, wi = wb & 3, si = wi >> 1, sj = wi & 1;

    if (t < 16) rsum_sh[t] = 0.f;
    for (int i = t; i < S_WIN; i += 512) {
        int r = i / 48, c = i - r * 48;
        codes[i] = (unsigned char)((si ? (r >= 12) : 0) | ((sj ? (c >= 24) : 0) << 1));
    }
    __syncthreads();

    bf16x8 qf[4];
    {
        const bf16x8* qb = qfrag + ((size_t)(wb * 72 + qt) * 4) * 64 + lane;
        #pragma unroll
        for (int kc = 0; kc < 4; ++kc) qf[kc] = qb[kc * 64];
    }
    const int qcode = codes[qt * 16 + (lane & 15)];
    char* Pb = (char*)Psh;
    float rsum = 0.f;

    // Phase 1: S^T = mfma(K, Q): col=q (lane&15), row=k
    for (int kt = 0; kt < 9; ++kt) {
        int Rk = w * 9 + kt;
        const bf16x8* kb = kfrag + ((size_t)(wb * 72 + Rk) * 4) * 64 + lane;
        bf16x8 kf[4];
        #pragma unroll
        for (int kc = 0; kc < 4; ++kc) kf[kc] = kb[kc * 64];
        int k0 = Rk * 16 + (lane >> 4) * 4;
        f32x4 acc = {0.f, 0.f, 0.f, 0.f};
        #pragma unroll
        for (int kc = 0; kc < 4; ++kc)
            acc = __builtin_amdgcn_mfma_f32_16x16x32_bf16(kf[kc], qf[kc], acc, 0, 0, 0);
        float ev[4];
        #pragma unroll
        for (int r = 0; r < 4; ++r) {
            ev[r] = (codes[k0 + r] == qcode) ? __expf(acc[r] * SCALE) : 0.f;
            rsum += ev[r];
        }
        unsigned lo = (unsigned)(unsigned short)f2bf(ev[0]) | ((unsigned)(unsigned short)f2bf(ev[1]) << 16);
        unsigned hi = (unsigned)(unsigned short)f2bf(ev[2]) | ((unsigned)(unsigned short)f2bf(ev[3]) << 16);
        int qloc = lane & 15;
        int off = (qloc * 2304 + k0 * 2) ^ ((qloc & 7) << 4);
        *(uint2*)(Pb + off) = make_uint2(lo, hi);
    }
    rsum += __shfl_xor(rsum, 16); rsum += __shfl_xor(rsum, 32);
    if (lane < 16) atomicAdd(&rsum_sh[lane], rsum);
    __syncthreads();

    // Phase 2: PV. wave w owns d-slice [w*16, w*16+16)
    f32x4 pv = {0.f, 0.f, 0.f, 0.f};
    const bf16x8* vb = vfrag + ((size_t)(wb * 8 + w) * 36) * 64 + lane;
    for (int kc = 0; kc < 36; ++kc) {
        int qloc = lane & 15;
        int off = (qloc * 2304 + kc * 64 + (lane >> 4) * 16) ^ ((qloc & 7) << 4);
        bf16x8 pf = *(const bf16x8*)(Pb + off);
        pv = __builtin_amdgcn_mfma_f32_16x16x32_bf16(pf, vb[kc * 64], pv, 0, 0, 0);
    }
    // epilogue
    #pragma unroll
    for (int r = 0; r < 4; ++r) {
        int qloc = (lane >> 4) * 4 + r;
        float val = pv[r] / rsum_sh[qloc];
        int qw = qt * 16 + qloc;
        int rr = qw / 48, cc2 = qw - rr * 48;
        int y = (si * 24 + rr + 12) % 48;
        int x = (sj * 48 + cc2 + 24) % 96;
        out[((size_t)bb * HW + y * 96 + x) * CC + w * 16 + (lane & 15)] = val;
    }
}

// ============ corr pass A: row/col exp-sums via MFMA ============
__global__ __launch_bounds__(256)
void corr_stats(const bf16x8* __restrict__ fragA, const bf16x8* __restrict__ fragB,
                float* __restrict__ rowsum, float* __restrict__ colsum)
{
    __shared__ float rs[128], cs[128];
    const int t = threadIdx.x, lane = t & 63, wave = t >> 6;
    const int wm = wave >> 1, wn = wave & 1;
    const int kt = blockIdx.x, qt = blockIdx.y, b = blockIdx.z;

    const bf16x8* Ab = fragA + (size_t)(b * 288 + qt * 8 + wm * 4) * 256 + lane;
    const bf16x8* Bb = fragB + (size_t)(b * 288 + kt * 8 + wn * 4) * 256 + lane;

    f32x4 acc[4][4] = {};
    #pragma unroll
    for (int kc = 0; kc < 4; ++kc) {
        bf16x8 a[4], bf[4];
        #pragma unroll
        for (int m = 0; m < 4; ++m) a[m]  = Ab[(m * 4 + kc) * 64];
        #pragma unroll
        for (int n = 0; n < 4; ++n) bf[n] = Bb[(n * 4 + kc) * 64];
        #pragma unroll
        for (int m = 0; m < 4; ++m)
            #pragma unroll
            for (int n = 0; n < 4; ++n)
                acc[m][n] = __builtin_amdgcn_mfma_f32_16x16x32_bf16(a[m], bf[n], acc[m][n], 0, 0, 0);
    }

    if (t < 128) { rs[t] = 0.f; cs[t] = 0.f; }
    __syncthreads();

    float cv[4] = {};
    #pragma unroll
    for (int m = 0; m < 4; ++m) {
        float rv[4] = {};
        #pragma unroll
        for (int n = 0; n < 4; ++n)
            #pragma unroll
            for (int r = 0; r < 4; ++r) {
                float ev = __expf(acc[m][n][r] * SCALE);
                rv[r] += ev; cv[n] += ev;
            }
        #pragma unroll
        for (int r = 0; r < 4; ++r) {
            float s = rv[r];
            s += __shfl_xor(s, 1); s += __shfl_xor(s, 2);
            s += __shfl_xor(s, 4); s += __shfl_xor(s, 8);
            if ((lane & 15) == 0)
                atomicAdd(&rs[wm * 64 + m * 16 + (lane >> 4) * 4 + r], s);
        }
    }
    #pragma unroll
    for (int n = 0; n < 4; ++n) {
        float s = cv[n];
        s += __shfl_xor(s, 16); s += __shfl_xor(s, 32);
        if (lane < 16) atomicAdd(&cs[wn * 64 + n * 16 + lane], s);
    }
    __syncthreads();
    if (t < 128)      atomicAdd(&rowsum[(size_t)b * HW + qt * 128 + t], rs[t]);
    else              atomicAdd(&colsum[(size_t)b * HW + kt * 128 + (t - 128)], cs[t - 128]);
}

// ============ corr pass B: dual_prob (dwordx4 via LDS transpose) + flow ============
__global__ __launch_bounds__(256)
void corr_final(const bf16x8* __restrict__ fragA, const bf16x8* __restrict__ fragB,
                const float* __restrict__ rowsum, const float* __restrict__ colsum,
                float* __restrict__ rowflow, float* __restrict__ colflow,
                float* __restrict__ dual)
{
    __shared__ float sfx[128], sfy[128], scx[128], scy[128];
    __shared__ float stg[4][16][68];    // per-wave 16x64 staging, pad 68
    const int t = threadIdx.x, lane = t & 63, wave = t >> 6;
    const int wm = wave >> 1, wn = wave & 1;
    const int kt = blockIdx.x, qt = blockIdx.y, b = blockIdx.z;

    const bf16x8* Ab = fragA + (size_t)(b * 288 + qt * 8 + wm * 4) * 256 + lane;
    const bf16x8* Bb = fragB + (size_t)(b * 288 + kt * 8 + wn * 4) * 256 + lane;

    f32x4 acc[4][4] = {};
    #pragma unroll
    for (int kc = 0; kc < 4; ++kc) {
        bf16x8 a[4], bf[4];
        #pragma unroll
        for (int m = 0; m < 4; ++m) a[m]  = Ab[(m * 4 + kc) * 64];
        #pragma unroll
        for (int n = 0; n < 4; ++n) bf[n] = Bb[(n * 4 + kc) * 64];
        #pragma unroll
        for (int m = 0; m < 4; ++m)
            #pragma unroll
            for (int n = 0; n < 4; ++n)
                acc[m][n] = __builtin_amdgcn_mfma_f32_16x16x32_bf16(a[m], bf[n], acc[m][n], 0, 0, 0);
    }

    if (t < 128) { sfx[t] = 0.f; sfy[t] = 0.f; scx[t] = 0.f; scy[t] = 0.f; }
    __syncthreads();

    const int qbase = qt * 128 + wm * 64;
    const int kbase = kt * 128 + wn * 64;

    float cinv[4], gkx[4], gky[4];
    #pragma unroll
    for (int n = 0; n < 4; ++n) {
        int k = kbase + n * 16 + (lane & 15);
        cinv[n] = 1.f / colsum[(size_t)b * HW + k];
        int kyi = k / W;
        gkx[n] = (float)(k - kyi * W); gky[n] = (float)kyi;
    }

    float cfx[4] = {}, cfy[4] = {};
    #pragma unroll
    for (int m = 0; m < 4; ++m) {
        float rinv[4], gqx[4], gqy[4];
        int q0 = qbase + m * 16 + (lane >> 4) * 4;
        #pragma unroll
        for (int r = 0; r < 4; ++r) {
            rinv[r] = 1.f / rowsum[(size_t)b * HW + q0 + r];
            int qyi = (q0 + r) / W;
            gqx[r] = (float)(q0 + r - qyi * W); gqy[r] = (float)qyi;
        }
        float rfx[4] = {}, rfy[4] = {};
        #pragma unroll
        for (int n = 0; n < 4; ++n) {
            #pragma unroll
            for (int r = 0; r < 4; ++r) {
                float ev = __expf(acc[m][n][r] * SCALE);
                float rp = ev * rinv[r];
                float ce = ev * cinv[n];
                stg[wave][(lane >> 4) * 4 + r][n * 16 + (lane & 15)] = rp * ce;
                rfx[r] += rp * gkx[n]; rfy[r] += rp * gky[n];
                cfx[n] += ce * gqx[r]; cfy[n] += ce * gqy[r];
            }
        }
        // drain 16x64 staged tile as 256B-contiguous dwordx4 stores
        #pragma unroll
        for (int pass = 0; pass < 4; ++pass) {
            int row = pass * 4 + (lane >> 4);
            float4 vv = *(const float4*)&stg[wave][row][(lane & 15) * 4];
            *(float4*)&dual[((size_t)b * HW + qbase + m * 16 + row) * HW + kbase + (lane & 15) * 4] = vv;
        }
        #pragma unroll
        for (int r = 0; r < 4; ++r) {
            float sx = rfx[r], sy = rfy[r];
            sx += __shfl_xor(sx, 1); sx += __shfl_xor(sx, 2);
            sx += __shfl_xor(sx, 4); sx += __shfl_xor(sx, 8);
            sy += __shfl_xor(sy, 1); sy += __shfl_xor(sy, 2);
            sy += __shfl_xor(sy, 4); sy += __shfl_xor(sy, 8);
            if ((lane & 15) == 0) {
                int row = wm * 64 + m * 16 + (lane >> 4) * 4 + r;
                atomicAdd(&sfx[row], sx); atomicAdd(&sfy[row], sy);
            }
        }
    }
    #pragma unroll
    for (int n = 0; n < 4; ++n) {
        float sx = cfx[n], sy = cfy[n];
        sx += __shfl_xor(sx, 16); sx += __shfl_xor(sx, 32);
        sy += __shfl_xor(sy, 16); sy += __shfl_xor(sy, 32);
        if (lane < 16) {
            int col = wn * 64 + n * 16 + lane;
            atomicAdd(&scx[col], sx); atomicAdd(&scy[col], sy);
        }
    }
    __syncthreads();
    if (t < 128) {
        atomicAdd(&rowflow[((size_t)b * HW + qt * 128 + t) * 2 + 0], sfx[t]);
        atomicAdd(&rowflow[((size_t)b * HW + qt * 128 + t) * 2 + 1], sfy[t]);
    } else {
        int j = t - 128;
        atomicAdd(&colflow[((size_t)b * HW + kt * 128 + j) * 2 + 0], scx[j]);
        atomicAdd(&colflow[((size_t)b * HW + kt * 128 + j) * 2 + 1], scy[j]);
    }
}

// ============ flow finalize ============
__global__ void flow_finalize(const float* __restrict__ rowflow, const float* __restrict__ colflow,
                              float* __restrict__ out)
{
    int i = blockIdx.x * 256 + threadIdx.x;
    if (i >= 2 * 2 * HW) return;
    int bb   = i / (2 * HW);
    int rem  = i % (2 * HW);
    int chan = rem / HW;
    int q    = rem % HW;
    float g = (chan == 0) ? (float)(q % W) : (float)(q / W);
    out[i]              = rowflow[((size_t)bb * HW + q) * 2 + chan] - g;
    out[2 * 2 * HW + i] = colflow[((size_t)bb * HW + q) * 2 + chan] - g;
}

extern "C" void kernel_launch(void* const* d_in, const int* in_sizes, int n_in,
                              void* d_out, int out_size, void* d_ws, size_t ws_size,
                              hipStream_t stream)
{
    (void)in_sizes; (void)n_in; (void)out_size; (void)ws_size;
    const float* q  = (const float*)d_in[0];
    const float* k  = (const float*)d_in[1];
    const float* v  = (const float*)d_in[2];
    const float* f0 = (const float*)d_in[3];
    const float* f1 = (const float*)d_in[4];

    float* out = (float*)d_out;
    const size_t ATTN_SZ = (size_t)2 * HW * CC;
    const size_t FLOW_SZ = (size_t)2 * 2 * HW;
    float* f01  = out + ATTN_SZ;
    float* dual = out + ATTN_SZ + 2 * FLOW_SZ;

    // ws: cfragA | cfragB | qfrag | kfrag | vfrag (each 2359296 B) | float accumulators
    const size_t FR = 2359296;
    char* wsb = (char*)d_ws;
    bf16x8* cfragA = (bf16x8*)(wsb);
    bf16x8* cfragB = (bf16x8*)(wsb + FR);
    bf16x8* qfrag  = (bf16x8*)(wsb + 2 * FR);
    bf16x8* kfrag  = (bf16x8*)(wsb + 3 * FR);
    bf16x8* vfrag  = (bf16x8*)(wsb + 4 * FR);
    float* wsf     = (float*)(wsb + 5 * FR);
    float* rowsum  = wsf;
    float* colsum  = wsf + 2 * HW;
    float* rowflow = wsf + 4 * HW;
    float* colflow = wsf + 8 * HW;

    prep_all<<<dim3(2016), 256, 0, stream>>>(q, k, v, f0, f1, cfragA, cfragB,
                                             qfrag, kfrag, vfrag, wsf);
    win_attn<<<dim3(72, 8), 512, 0, stream>>>(qfrag, kfrag, vfrag, out);
    corr_stats<<<dim3(36, 36, 2), 256, 0, stream>>>(cfragA, cfragB, rowsum, colsum);
    corr_final<<<dim3(36, 36, 2), 256, 0, stream>>>(cfragA, cfragB, rowsum, colsum,
                                                    rowflow, colflow, dual);
    flow_finalize<<<dim3(72), 256, 0, stream>>>(rowflow, colflow, f01);
}

// Round 6
// 113.791 us; speedup vs baseline: 8.3215x; 1.1760x over previous
//
#include <hip/hip_runtime.h>

#define HW 4608
#define CC 128
#define H 48
#define W 96
#define S_WIN 1152
#define SCALE 0.08838834764831845f  // 1/sqrt(128)

typedef __attribute__((ext_vector_type(8))) short bf16x8;
typedef __attribute__((ext_vector_type(4))) float f32x4;

static __device__ inline short f2bf(float f) {
    unsigned u = __builtin_bit_cast(unsigned, f);
    unsigned r = (u + 0x7fff + ((u >> 16) & 1)) >> 16;   // RNE
    return (short)r;
}

// ============ merged prep: corr frags + qkv frags + ws zeroing ============
__global__ __launch_bounds__(256)
void prep_all(const float* __restrict__ Q, const float* __restrict__ K, const float* __restrict__ V,
              const float* __restrict__ f0, const float* __restrict__ f1,
              bf16x8* __restrict__ cfragA, bf16x8* __restrict__ cfragB,
              bf16x8* __restrict__ qfrag, bf16x8* __restrict__ kfrag, bf16x8* __restrict__ vfrag,
              float* __restrict__ wsf)
{
    __shared__ float vt[32][132];
    const int bx = blockIdx.x;
    const int t = threadIdx.x;

    if (bx < 1152) {
        int zi = bx * 256 + t;
        if (zi < 12 * HW) wsf[zi] = 0.f;
        // ---- corr prep ----
        const int pt = bx % 72;
        const int z  = bx / 72;
        const int tensor = z >> 3, b = (z >> 2) & 1, kc = z & 3;
        const float* src = (tensor ? f1 : f0) + (size_t)b * CC * HW + (size_t)kc * 32 * HW + pt * 64;
        {
            int ch = t >> 4;
            int c4 = (t & 15) * 4;
            *(float4*)&vt[ch][c4]      = *(const float4*)&src[(size_t)ch * HW + c4];
            *(float4*)&vt[ch + 16][c4] = *(const float4*)&src[(size_t)(ch + 16) * HW + c4];
        }
        __syncthreads();
        int Rloc = t >> 6, lane = t & 63;
        int R = pt * 4 + Rloc;
        bf16x8 v;
        #pragma unroll
        for (int j = 0; j < 8; ++j) v[j] = f2bf(vt[(lane >> 4) * 8 + j][Rloc * 16 + (lane & 15)]);
        (tensor ? cfragB : cfragA)[((size_t)(b * 288 + R) * 4 + kc) * 64 + lane] = v;
    } else {
        // ---- qkv prep ----
        const int bx2 = bx - 1152;
        const int R2 = bx2 % 36;
        const int z  = bx2 / 36;
        const int tensor = z >> 3, wb = z & 7;
        const int bb = wb >> 2, wi = wb & 3, si = wi >> 1, sj = wi & 1;
        const float* src = (tensor == 0 ? Q : (tensor == 1 ? K : V)) + (size_t)bb * HW * CC;
        {
            int row = t >> 3;
            int c16 = (t & 7) * 16;
            int qw = R2 * 32 + row;
            int rr = qw / 48, cc = qw - rr * 48;
            int y = (si * 24 + rr + 12) % 48;
            int x = (sj * 48 + cc + 24) % 96;
            const float* rp = src + ((size_t)y * 96 + x) * CC + c16;
            #pragma unroll
            for (int u = 0; u < 4; ++u)
                *(float4*)&vt[row][c16 + u * 4] = *(const float4*)&rp[u * 4];
        }
        __syncthreads();
        if (tensor < 2) {
            bf16x8* frag = tensor == 0 ? qfrag : kfrag;
            #pragma unroll
            for (int e2 = 0; e2 < 2; ++e2) {
                int e = t + e2 * 256;
                int Rloc = e >> 8, kc = (e >> 6) & 3, lane = e & 63;
                int R = R2 * 2 + Rloc;
                bf16x8 v;
                #pragma unroll
                for (int j = 0; j < 8; ++j)
                    v[j] = f2bf(vt[Rloc * 16 + (lane & 15)][kc * 32 + (lane >> 4) * 8 + j]);
                frag[((size_t)(wb * 72 + R) * 4 + kc) * 64 + lane] = v;
            }
        } else {
            #pragma unroll
            for (int e2 = 0; e2 < 2; ++e2) {
                int e = t + e2 * 256;
                int dB = e >> 6, lane = e & 63;
                bf16x8 v;
                #pragma unroll
                for (int j = 0; j < 8; ++j)
                    v[j] = f2bf(vt[(lane >> 4) * 8 + j][dB * 16 + (lane & 15)]);
                vfrag[((size_t)(wb * 8 + dB) * 36 + R2) * 64 + lane] = v;
            }
        }
    }
}

// ============ fused: window attention (blocks 0..575) + corr pass A (576..3167) ============
__global__ __launch_bounds__(256)
void fused_ws(const bf16x8* __restrict__ qfrag, const bf16x8* __restrict__ kfrag,
              const bf16x8* __restrict__ vfrag, float* __restrict__ out,
              const bf16x8* __restrict__ cfragA, const bf16x8* __restrict__ cfragB,
              float* __restrict__ rowsum, float* __restrict__ colsum)
{
    __shared__ __align__(16) char smem[38144];
    const int bx = blockIdx.x;
    const int t = threadIdx.x, lane = t & 63, w = t >> 6;

    if (bx < 576) {
        // ================= window attention, 16-q-row tile, 4 waves =================
        short* Psh = (short*)smem;                         // 16*1152*2 = 36864 B
        unsigned char* codes = (unsigned char*)(smem + 36864);   // 1152 B
        float* rsum_sh = (float*)(smem + 38016);           // 64 B
        const int qt = bx % 72, wb = bx / 72;
        const int bb = wb >> 2, wi = wb & 3, si = wi >> 1, sj = wi & 1;

        if (t < 16) rsum_sh[t] = 0.f;
        for (int i = t; i < S_WIN; i += 256) {
            int r = i / 48, c = i - r * 48;
            codes[i] = (unsigned char)((si ? (r >= 12) : 0) | ((sj ? (c >= 24) : 0) << 1));
        }
        __syncthreads();

        bf16x8 qf[4];
        {
            const bf16x8* qb = qfrag + ((size_t)(wb * 72 + qt) * 4) * 64 + lane;
            #pragma unroll
            for (int kc = 0; kc < 4; ++kc) qf[kc] = qb[kc * 64];
        }
        const int qcode = codes[qt * 16 + (lane & 15)];
        char* Pb = (char*)Psh;
        float rsum = 0.f;

        // Phase 1: S^T = mfma(K, Q): col=q (lane&15), row=k. wave w covers Rk w*18..+18
        for (int kt = 0; kt < 18; ++kt) {
            int Rk = w * 18 + kt;
            const bf16x8* kb = kfrag + ((size_t)(wb * 72 + Rk) * 4) * 64 + lane;
            bf16x8 kf[4];
            #pragma unroll
            for (int kc = 0; kc < 4; ++kc) kf[kc] = kb[kc * 64];
            int k0 = Rk * 16 + (lane >> 4) * 4;
            f32x4 acc = {0.f, 0.f, 0.f, 0.f};
            #pragma unroll
            for (int kc = 0; kc < 4; ++kc)
                acc = __builtin_amdgcn_mfma_f32_16x16x32_bf16(kf[kc], qf[kc], acc, 0, 0, 0);
            float ev[4];
            #pragma unroll
            for (int r = 0; r < 4; ++r) {
                ev[r] = (codes[k0 + r] == qcode) ? __expf(acc[r] * SCALE) : 0.f;
                rsum += ev[r];
            }
            unsigned lo = (unsigned)(unsigned short)f2bf(ev[0]) | ((unsigned)(unsigned short)f2bf(ev[1]) << 16);
            unsigned hi = (unsigned)(unsigned short)f2bf(ev[2]) | ((unsigned)(unsigned short)f2bf(ev[3]) << 16);
            int qloc = lane & 15;
            int off = (qloc * 2304 + k0 * 2) ^ ((qloc & 7) << 4);
            *(uint2*)(Pb + off) = make_uint2(lo, hi);
        }
        rsum += __shfl_xor(rsum, 16); rsum += __shfl_xor(rsum, 32);
        if (lane < 16) atomicAdd(&rsum_sh[lane], rsum);
        __syncthreads();

        // Phase 2: PV. wave w owns d-slices w*16 and (w+4)*16
        f32x4 pv0 = {0.f, 0.f, 0.f, 0.f}, pv1 = {0.f, 0.f, 0.f, 0.f};
        const bf16x8* vb0 = vfrag + ((size_t)(wb * 8 + w) * 36) * 64 + lane;
        const bf16x8* vb1 = vfrag + ((size_t)(wb * 8 + w + 4) * 36) * 64 + lane;
        for (int kc = 0; kc < 36; ++kc) {
            int qloc = lane & 15;
            int off = (qloc * 2304 + kc * 64 + (lane >> 4) * 16) ^ ((qloc & 7) << 4);
            bf16x8 pf = *(const bf16x8*)(Pb + off);
            pv0 = __builtin_amdgcn_mfma_f32_16x16x32_bf16(pf, vb0[kc * 64], pv0, 0, 0, 0);
            pv1 = __builtin_amdgcn_mfma_f32_16x16x32_bf16(pf, vb1[kc * 64], pv1, 0, 0, 0);
        }
        #pragma unroll
        for (int r = 0; r < 4; ++r) {
            int qloc = (lane >> 4) * 4 + r;
            float rinv = 1.f / rsum_sh[qloc];
            int qw = qt * 16 + qloc;
            int rr = qw / 48, cc2 = qw - rr * 48;
            int y = (si * 24 + rr + 12) % 48;
            int x = (sj * 48 + cc2 + 24) % 96;
            float* op = &out[((size_t)bb * HW + y * 96 + x) * CC + (lane & 15)];
            op[w * 16]       = pv0[r] * rinv;
            op[(w + 4) * 16] = pv1[r] * rinv;
        }
    } else {
        // ================= corr pass A: row/col exp-sums =================
        float* rs = (float*)smem;            // 128 floats
        float* cs = (float*)(smem + 512);    // 128 floats
        const int bx2 = bx - 576;
        const int kt = bx2 % 36, qt = (bx2 / 36) % 36, b = bx2 / 1296;
        const int wm = w >> 1, wn = w & 1;

        const bf16x8* Ab = cfragA + (size_t)(b * 288 + qt * 8 + wm * 4) * 256 + lane;
        const bf16x8* Bb = cfragB + (size_t)(b * 288 + kt * 8 + wn * 4) * 256 + lane;

        f32x4 acc[4][4] = {};
        #pragma unroll
        for (int kc = 0; kc < 4; ++kc) {
            bf16x8 a[4], bf[4];
            #pragma unroll
            for (int m = 0; m < 4; ++m) a[m]  = Ab[(m * 4 + kc) * 64];
            #pragma unroll
            for (int n = 0; n < 4; ++n) bf[n] = Bb[(n * 4 + kc) * 64];
            #pragma unroll
            for (int m = 0; m < 4; ++m)
                #pragma unroll
                for (int n = 0; n < 4; ++n)
                    acc[m][n] = __builtin_amdgcn_mfma_f32_16x16x32_bf16(a[m], bf[n], acc[m][n], 0, 0, 0);
        }

        if (t < 128) { rs[t] = 0.f; cs[t] = 0.f; }
        __syncthreads();

        float cv[4] = {};
        #pragma unroll
        for (int m = 0; m < 4; ++m) {
            float rv[4] = {};
            #pragma unroll
            for (int n = 0; n < 4; ++n)
                #pragma unroll
                for (int r = 0; r < 4; ++r) {
                    float ev = __expf(acc[m][n][r] * SCALE);
                    rv[r] += ev; cv[n] += ev;
                }
            #pragma unroll
            for (int r = 0; r < 4; ++r) {
                float s = rv[r];
                s += __shfl_xor(s, 1); s += __shfl_xor(s, 2);
                s += __shfl_xor(s, 4); s += __shfl_xor(s, 8);
                if ((lane & 15) == 0)
                    atomicAdd(&rs[wm * 64 + m * 16 + (lane >> 4) * 4 + r], s);
            }
        }
        #pragma unroll
        for (int n = 0; n < 4; ++n) {
            float s = cv[n];
            s += __shfl_xor(s, 16); s += __shfl_xor(s, 32);
            if (lane < 16) atomicAdd(&cs[wn * 64 + n * 16 + lane], s);
        }
        __syncthreads();
        if (t < 128)      atomicAdd(&rowsum[(size_t)b * HW + qt * 128 + t], rs[t]);
        else              atomicAdd(&colsum[(size_t)b * HW + kt * 128 + (t - 128)], cs[t - 128]);
    }
}

// ============ corr pass B: dual_prob (nontemporal dwordx4 via LDS transpose) + flow ============
__global__ __launch_bounds__(256)
void corr_final(const bf16x8* __restrict__ fragA, const bf16x8* __restrict__ fragB,
                const float* __restrict__ rowsum, const float* __restrict__ colsum,
                float* __restrict__ rowflow, float* __restrict__ colflow,
                float* __restrict__ dual)
{
    __shared__ float sfx[128], sfy[128], scx[128], scy[128];
    __shared__ float stg[4][16][68];
    const int t = threadIdx.x, lane = t & 63, wave = t >> 6;
    const int wm = wave >> 1, wn = wave & 1;
    const int kt = blockIdx.x, qt = blockIdx.y, b = blockIdx.z;

    const bf16x8* Ab = fragA + (size_t)(b * 288 + qt * 8 + wm * 4) * 256 + lane;
    const bf16x8* Bb = fragB + (size_t)(b * 288 + kt * 8 + wn * 4) * 256 + lane;

    f32x4 acc[4][4] = {};
    #pragma unroll
    for (int kc = 0; kc < 4; ++kc) {
        bf16x8 a[4], bf[4];
        #pragma unroll
        for (int m = 0; m < 4; ++m) a[m]  = Ab[(m * 4 + kc) * 64];
        #pragma unroll
        for (int n = 0; n < 4; ++n) bf[n] = Bb[(n * 4 + kc) * 64];
        #pragma unroll
        for (int m = 0; m < 4; ++m)
            #pragma unroll
            for (int n = 0; n < 4; ++n)
                acc[m][n] = __builtin_amdgcn_mfma_f32_16x16x32_bf16(a[m], bf[n], acc[m][n], 0, 0, 0);
    }

    if (t < 128) { sfx[t] = 0.f; sfy[t] = 0.f; scx[t] = 0.f; scy[t] = 0.f; }
    __syncthreads();

    const int qbase = qt * 128 + wm * 64;
    const int kbase = kt * 128 + wn * 64;

    float cinv[4], gkx[4], gky[4];
    #pragma unroll
    for (int n = 0; n < 4; ++n) {
        int k = kbase + n * 16 + (lane & 15);
        cinv[n] = 1.f / colsum[(size_t)b * HW + k];
        int kyi = k / W;
        gkx[n] = (float)(k - kyi * W); gky[n] = (float)kyi;
    }

    float cfx[4] = {}, cfy[4] = {};
    #pragma unroll
    for (int m = 0; m < 4; ++m) {
        float rinv[4], gqx[4], gqy[4];
        int q0 = qbase + m * 16 + (lane >> 4) * 4;
        #pragma unroll
        for (int r = 0; r < 4; ++r) {
            rinv[r] = 1.f / rowsum[(size_t)b * HW + q0 + r];
            int qyi = (q0 + r) / W;
            gqx[r] = (float)(q0 + r - qyi * W); gqy[r] = (float)qyi;
        }
        float rfx[4] = {}, rfy[4] = {};
        #pragma unroll
        for (int n = 0; n < 4; ++n) {
            #pragma unroll
            for (int r = 0; r < 4; ++r) {
                float ev = __expf(acc[m][n][r] * SCALE);
                float rp = ev * rinv[r];
                float ce = ev * cinv[n];
                stg[wave][(lane >> 4) * 4 + r][n * 16 + (lane & 15)] = rp * ce;
                rfx[r] += rp * gkx[n]; rfy[r] += rp * gky[n];
                cfx[n] += ce * gqx[r]; cfy[n] += ce * gqy[r];
            }
        }
        #pragma unroll
        for (int pass = 0; pass < 4; ++pass) {
            int row = pass * 4 + (lane >> 4);
            f32x4 vv = *(const f32x4*)&stg[wave][row][(lane & 15) * 4];
            __builtin_nontemporal_store(vv,
                (f32x4*)&dual[((size_t)b * HW + qbase + m * 16 + row) * HW + kbase + (lane & 15) * 4]);
        }
        #pragma unroll
        for (int r = 0; r < 4; ++r) {
            float sx = rfx[r], sy = rfy[r];
            sx += __shfl_xor(sx, 1); sx += __shfl_xor(sx, 2);
            sx += __shfl_xor(sx, 4); sx += __shfl_xor(sx, 8);
            sy += __shfl_xor(sy, 1); sy += __shfl_xor(sy, 2);
            sy += __shfl_xor(sy, 4); sy += __shfl_xor(sy, 8);
            if ((lane & 15) == 0) {
                int row = wm * 64 + m * 16 + (lane >> 4) * 4 + r;
                atomicAdd(&sfx[row], sx); atomicAdd(&sfy[row], sy);
            }
        }
    }
    #pragma unroll
    for (int n = 0; n < 4; ++n) {
        float sx = cfx[n], sy = cfy[n];
        sx += __shfl_xor(sx, 16); sx += __shfl_xor(sx, 32);
        sy += __shfl_xor(sy, 16); sy += __shfl_xor(sy, 32);
        if (lane < 16) {
            int col = wn * 64 + n * 16 + lane;
            atomicAdd(&scx[col], sx); atomicAdd(&scy[col], sy);
        }
    }
    __syncthreads();
    if (t < 128) {
        atomicAdd(&rowflow[((size_t)b * HW + qt * 128 + t) * 2 + 0], sfx[t]);
        atomicAdd(&rowflow[((size_t)b * HW + qt * 128 + t) * 2 + 1], sfy[t]);
    } else {
        int j = t - 128;
        atomicAdd(&colflow[((size_t)b * HW + kt * 128 + j) * 2 + 0], scx[j]);
        atomicAdd(&colflow[((size_t)b * HW + kt * 128 + j) * 2 + 1], scy[j]);
    }
}

// ============ flow finalize ============
__global__ void flow_finalize(const float* __restrict__ rowflow, const float* __restrict__ colflow,
                              float* __restrict__ out)
{
    int i = blockIdx.x * 256 + threadIdx.x;
    if (i >= 2 * 2 * HW) return;
    int bb   = i / (2 * HW);
    int rem  = i % (2 * HW);
    int chan = rem / HW;
    int q    = rem % HW;
    float g = (chan == 0) ? (float)(q % W) : (float)(q / W);
    out[i]              = rowflow[((size_t)bb * HW + q) * 2 + chan] - g;
    out[2 * 2 * HW + i] = colflow[((size_t)bb * HW + q) * 2 + chan] - g;
}

extern "C" void kernel_launch(void* const* d_in, const int* in_sizes, int n_in,
                              void* d_out, int out_size, void* d_ws, size_t ws_size,
                              hipStream_t stream)
{
    (void)in_sizes; (void)n_in; (void)out_size; (void)ws_size;
    const float* q  = (const float*)d_in[0];
    const float* k  = (const float*)d_in[1];
    const float* v  = (const float*)d_in[2];
    const float* f0 = (const float*)d_in[3];
    const float* f1 = (const float*)d_in[4];

    float* out = (float*)d_out;
    const size_t ATTN_SZ = (size_t)2 * HW * CC;
    const size_t FLOW_SZ = (size_t)2 * 2 * HW;
    float* f01  = out + ATTN_SZ;
    float* dual = out + ATTN_SZ + 2 * FLOW_SZ;

    const size_t FR = 2359296;
    char* wsb = (char*)d_ws;
    bf16x8* cfragA = (bf16x8*)(wsb);
    bf16x8* cfragB = (bf16x8*)(wsb + FR);
    bf16x8* qfrag  = (bf16x8*)(wsb + 2 * FR);
    bf16x8* kfrag  = (bf16x8*)(wsb + 3 * FR);
    bf16x8* vfrag  = (bf16x8*)(wsb + 4 * FR);
    float* wsf     = (float*)(wsb + 5 * FR);
    float* rowsum  = wsf;
    float* colsum  = wsf + 2 * HW;
    float* rowflow = wsf + 4 * HW;
    float* colflow = wsf + 8 * HW;

    prep_all<<<dim3(2016), 256, 0, stream>>>(q, k, v, f0, f1, cfragA, cfragB,
                                             qfrag, kfrag, vfrag, wsf);
    fused_ws<<<dim3(576 + 2592), 256, 0, stream>>>(qfrag, kfrag, vfrag, out,
                                                   cfragA, cfragB, rowsum, colsum);
    corr_final<<<dim3(36, 36, 2), 256, 0, stream>>>(cfragA, cfragB, rowsum, colsum,
                                                    rowflow, colflow, dual);
    flow_finalize<<<dim3(72), 256, 0, stream>>>(rowflow, colflow, f01);
}